// Round 7
// baseline (2406.969 us; speedup 1.0000x reference)
//
#include <hip/hip_runtime.h>
#include <stdint.h>
#include <string.h>

// Problem dims (fixed by the reference)
#define BDIM   4096
#define INDIM  1024
#define XDIM   2048
#define OUTDIM 512

#define LO_SCALE 2048.0f         // 2^11: lifts fp16 lo-plane out of subnormals
#define INV_LO_SCALE (1.0f / 2048.0f)

typedef _Float16 f16x8 __attribute__((ext_vector_type(8)));
typedef float f32x4 __attribute__((ext_vector_type(4)));

__device__ __forceinline__ unsigned short h2u(_Float16 h) {
  unsigned short u;
  memcpy(&u, &h, 2);
  return u;
}

// split f32 into hi fp16 + scaled-lo fp16 (combined ~22 mantissa bits)
__device__ __forceinline__ void split_h(float v, unsigned short& h,
                                        unsigned short& l) {
  _Float16 hh = (_Float16)v;                       // RTNE
  float r = v - (float)hh;                         // exact
  _Float16 ll = (_Float16)(r * LO_SCALE);          // |r|*2^11 <= |v|, no inf
  h = h2u(hh);
  l = h2u(ll);
}

// async global->LDS, 16B per lane; LDS dest wave-uniform base + lane*16
__device__ __forceinline__ void gld_lds16(const void* g, void* l) {
  __builtin_amdgcn_global_load_lds(
      (const __attribute__((address_space(1))) uint32_t*)g,
      (__attribute__((address_space(3))) uint32_t*)l, 16, 0, 0);
}

// fused RandomActivation + clip (relu/sigmoid/tanh/leaky(.1)/selu), libm-grade
__device__ __forceinline__ float rand_act(float v, int a, float mo) {
  float r;
  if (a == 0) {
    r = fmaxf(v, 0.0f);
  } else if (a == 1) {
    r = 1.0f / (1.0f + expf(-v));
  } else if (a == 2) {
    r = tanhf(v);
  } else if (a == 3) {
    r = (v >= 0.0f) ? v : 0.1f * v;
  } else {  // selu (matches jax: scale * where(v>0, v, alpha*expm1(v)))
    r = (v > 0.0f) ? 1.0507009873554805f * v
                   : 1.7580993408473766f * expm1f(v);
  }
  return fminf(r, mo);
}

// x (f32) -> hi/scaled-lo fp16 planes, 4 elems/thread
__global__ void cvt_split(const float* __restrict__ s,
                          unsigned short* __restrict__ dh,
                          unsigned short* __restrict__ dl, int n) {
  int i = (blockIdx.x * blockDim.x + threadIdx.x) * 4;
  if (i >= n) return;
  float4 v = *(const float4*)(s + i);
  ushort4 h, l;
  split_h(v.x, h.x, l.x);
  split_h(v.y, h.y, l.y);
  split_h(v.z, h.z, l.z);
  split_h(v.w, h.w, l.w);
  *(ushort4*)(dh + i) = h;
  *(ushort4*)(dl + i) = l;
}

// W (K x N, f32, row-major) -> WT hi/scaled-lo fp16 (N x K, row-major)
__global__ void transpose_cvt_split(const float* __restrict__ W,
                                    unsigned short* __restrict__ WTh,
                                    unsigned short* __restrict__ WTl, int K,
                                    int N) {
  __shared__ float t[32][33];
  int n0 = blockIdx.x * 32, k0 = blockIdx.y * 32;
  int tx = threadIdx.x, ty = threadIdx.y;  // 32 x 8
#pragma unroll
  for (int i = 0; i < 32; i += 8)
    t[ty + i][tx] = W[(size_t)(k0 + ty + i) * N + n0 + tx];
  __syncthreads();
#pragma unroll
  for (int i = 0; i < 32; i += 8) {
    float v = t[tx][ty + i];
    unsigned short h, l;
    split_h(v, h, l);
    size_t idx = (size_t)(n0 + ty + i) * K + k0 + tx;
    WTh[idx] = h;
    WTl[idx] = l;
  }
}

// C[M,N] = act( A[M,K] @ BT[N,K]^T + bias ), split-fp16 (3-term) precision.
// acc1 = hi*hi; acc2 = hi*lo' + lo'*hi at scale 2^11. Final = acc1+acc2/2^11.
//
// Round-7 structure (empirical law from R3-R6: co-resident blocks/CU rules;
// R6's 48KB LDS silently dropped to 2 blocks/CU):
//  - A-only in LDS, double-buffered FRAGMENT-order: 2 x 8 KB = 16 KB total.
//    Every wave fragment read is one contiguous 1-KB ds_read_b128
//    (conflict-free, R5/R6-verified). A is the only tensor with cross-wave
//    reuse (all 4 waves read it) -> the only one worth LDS.
//  - B fragments: global -> VGPR with ONE-STEP register prefetch. B-tiles had
//    zero cross-wave reuse; R5 failed only because B drained same-step.
//    Here stage(k+1)+loadB(k+1) are issued BEFORE compute(k), so the barrier
//    drain (vmcnt(0)) is overlapped by a full compute phase.
//  - one __syncthreads per K-step (A dbuf), not two.
// Block tile 64x128, BK=32, 4 waves (wave-tile 64x32). Grid (N/128, M/64) ->
// 4 blocks/CU grid-limited, LDS 16KB and VGPR<=128 keep them all resident.
template <bool OUT_F16>
__global__ __launch_bounds__(256, 4) void gemm_split_act(
    const short* __restrict__ A1h, const short* __restrict__ A1l,
    const short* __restrict__ A2h, const short* __restrict__ A2l,
    const short* __restrict__ BTh, const short* __restrict__ BTl,
    const float* __restrict__ bias, const float* __restrict__ mo,
    const int* __restrict__ aid, unsigned short* __restrict__ Ch,
    unsigned short* __restrict__ Cl, float* __restrict__ Cf, int N, int K,
    int Ksplit) {
  // A double-buffer: [plane(2)][t(4)][512 halfs] each = 8 KB each
  __shared__ short lA0[8 * 512];
  __shared__ short lA1[8 * 512];

  const int tid = threadIdx.x;
  const int lane = tid & 63;
  const int wave = tid >> 6;        // 0..3 = n-strip of wave
  const int m16 = lane & 15, quad = lane >> 4;

  const int blockN = blockIdx.x * 128;
  const int blockM = blockIdx.y * 64;

  f32x4 acc1[4][2];  // hi*hi
  f32x4 acc2[4][2];  // (hi*lo' + lo'*hi), scale 2^11
#pragma unroll
  for (int i = 0; i < 4; i++)
#pragma unroll
    for (int j = 0; j < 2; j++) {
      acc1[i][j] = (f32x4){0.f, 0.f, 0.f, 0.f};
      acc2[i][j] = (f32x4){0.f, 0.f, 0.f, 0.f};
    }

  const int KSTEPS = K >> 5;  // 32 / 64 / 128 — always even

  // B fragment global row bases for this wave's two 16-col groups
  const size_t bRow0 = (size_t)(blockN + wave * 32 + m16) * K + quad * 8;
  const size_t bRow1 = (size_t)(blockN + wave * 32 + 16 + m16) * K + quad * 8;

  // stage A for K-step ks into dA: 8 chunks of 1 KB (0-3 hi t, 4-7 lo t),
  // 2 per wave; staging lane i writes exactly what compute lane i reads.
  auto stageA = [&](int ks, short* dA) {
    int k0 = ks << 5;
    const short *Akh, *Akl;
    int koff, lda;
    if (k0 < Ksplit) {
      Akh = A1h; Akl = A1l; koff = k0; lda = Ksplit;
    } else {
      Akh = A2h; Akl = A2l; koff = k0 - Ksplit; lda = K - Ksplit;
    }
#pragma unroll
    for (int s = 0; s < 2; s++) {
      int g = wave * 2 + s;            // 0..7
      int t = g & 3;
      const short* base = (g < 4) ? Akh : Akl;
      const short* src =
          base + (size_t)(blockM + t * 16 + m16) * lda + koff + quad * 8;
      gld_lds16(src, dA + g * 512);
    }
  };

  // load B fragments for K-step ks into a register set
  auto loadB = [&](int ks, f16x8* bH, f16x8* bL) {
    size_t ko = (size_t)(ks << 5);
    bH[0] = *(const f16x8*)(BTh + bRow0 + ko);
    bH[1] = *(const f16x8*)(BTh + bRow1 + ko);
    bL[0] = *(const f16x8*)(BTl + bRow0 + ko);
    bL[1] = *(const f16x8*)(BTl + bRow1 + ko);
  };

  // compute one K-step from (sA, bH, bL)
  auto compute = [&](const short* sA, const f16x8* bH, const f16x8* bL) {
    f16x8 aH[4];
#pragma unroll
    for (int t = 0; t < 4; t++)
      aH[t] = *(const f16x8*)&sA[t * 512 + lane * 8];
    // phase 1: hi x hi -> acc1
#pragma unroll
    for (int i = 0; i < 4; i++)
#pragma unroll
      for (int j = 0; j < 2; j++)
        acc1[i][j] = __builtin_amdgcn_mfma_f32_16x16x32_f16(aH[i], bH[j],
                                                            acc1[i][j], 0, 0, 0);
    // phase 2: hi x lo' -> acc2
#pragma unroll
    for (int i = 0; i < 4; i++)
#pragma unroll
      for (int j = 0; j < 2; j++)
        acc2[i][j] = __builtin_amdgcn_mfma_f32_16x16x32_f16(aH[i], bL[j],
                                                            acc2[i][j], 0, 0, 0);
    // phase 3: lo' x hi -> acc2
    {
      f16x8 aL[4];
#pragma unroll
      for (int t = 0; t < 4; t++)
        aL[t] = *(const f16x8*)&sA[(4 + t) * 512 + lane * 8];
#pragma unroll
      for (int i = 0; i < 4; i++)
#pragma unroll
        for (int j = 0; j < 2; j++)
          acc2[i][j] = __builtin_amdgcn_mfma_f32_16x16x32_f16(
              aL[i], bH[j], acc2[i][j], 0, 0, 0);
    }
  };

  f16x8 bH0[2], bL0[2], bH1[2], bL1[2];

  // prologue: fill buf0 + Breg0 (full latency once)
  stageA(0, lA0);
  loadB(0, bH0, bL0);
  __syncthreads();

  for (int ks = 0; ks < KSTEPS; ks += 2) {
    // prefetch step ks+1, then compute ks: the barrier drain below is
    // overlapped by ~1 full compute phase of MFMA+ds_read work.
    if (ks + 1 < KSTEPS) {
      stageA(ks + 1, lA1);
      loadB(ks + 1, bH1, bL1);
    }
    compute(lA0, bH0, bL0);
    __syncthreads();  // drains stage(ks+1)+loadB(ks+1); buf0 free
    if (ks + 2 < KSTEPS) {
      stageA(ks + 2, lA0);
      loadB(ks + 2, bH0, bL0);
    }
    compute(lA1, bH1, bL1);
    __syncthreads();  // drains stage(ks+2)+loadB(ks+2); buf1 free
  }

  // epilogue: combine accs, bias + per-column activation + clip
  // C/D map col=lane&15, row=quad*4+reg (m89-verified)
#pragma unroll
  for (int j = 0; j < 2; j++) {
    int col = blockN + wave * 32 + j * 16 + m16;
    float b = bias[col];
    float m = mo[col];
    int a = aid[col];
#pragma unroll
    for (int i = 0; i < 4; i++) {
#pragma unroll
      for (int r = 0; r < 4; r++) {
        int row = blockM + i * 16 + quad * 4 + r;
        float s = acc1[i][j][r] + acc2[i][j][r] * INV_LO_SCALE;
        float v = rand_act(s + b, a, m);
        size_t idx = (size_t)row * N + col;
        if (OUT_F16) {
          unsigned short h, l;
          split_h(v, h, l);
          Ch[idx] = h;
          Cl[idx] = l;
        } else {
          Cf[idx] = v;
        }
      }
    }
  }
}

extern "C" void kernel_launch(void* const* d_in, const int* in_sizes, int n_in,
                              void* d_out, int out_size, void* d_ws,
                              size_t ws_size, hipStream_t stream) {
  (void)in_sizes; (void)n_in; (void)out_size; (void)ws_size;

  const float* x     = (const float*)d_in[0];
  const float* W_in  = (const float*)d_in[1];
  const float* b_in  = (const float*)d_in[2];
  const float* Wh[6] = {(const float*)d_in[3], (const float*)d_in[4],
                        (const float*)d_in[5], (const float*)d_in[6],
                        (const float*)d_in[7], (const float*)d_in[8]};
  const float* bh    = (const float*)d_in[9];
  const float* W_out = (const float*)d_in[10];
  const float* b_out = (const float*)d_in[11];
  const float* mo_in = (const float*)d_in[12];
  const float* mo_h  = (const float*)d_in[13];
  const float* mo_out= (const float*)d_in[14];
  const int* aid_in  = (const int*)d_in[15];
  const int* aid_h   = (const int*)d_in[16];
  const int* aid_out = (const int*)d_in[17];

  const int hin[6] = {XDIM, XDIM, 2 * XDIM, XDIM, 2 * XDIM, XDIM};

  // workspace layout (~264 MB); each tensor = hi plane then lo plane
  char* p = (char*)d_ws;
  auto take = [&](size_t elems) {
    short* q = (short*)p;
    p += elems * 2 * 2;  // hi + lo, 2B each
    return q;
  };
  short* x_s = take((size_t)BDIM * INDIM);
  size_t xpl = (size_t)BDIM * INDIM;
  short* w_in_s = take((size_t)XDIM * INDIM);
  size_t wpl_in = (size_t)XDIM * INDIM;
  short* w_h_s[6];
  size_t wpl_h[6];
  for (int i = 0; i < 6; i++) {
    wpl_h[i] = (size_t)XDIM * hin[i];
    w_h_s[i] = take(wpl_h[i]);
  }
  short* w_out_s = take((size_t)OUTDIM * XDIM);
  size_t wpl_out = (size_t)OUTDIM * XDIM;
  const size_t apl = (size_t)BDIM * XDIM;  // activation plane
  short* actA = take(apl);
  short* actB = take(apl);
  short* actC = take(apl);

  // 1) convert x -> hi/lo fp16
  {
    int n = BDIM * INDIM;
    cvt_split<<<dim3(n / 4 / 256), dim3(256), 0, stream>>>(
        x, (unsigned short*)x_s, (unsigned short*)(x_s + xpl), n);
  }
  // 2) transpose+split all weights: W(K,N) -> WT(N,K) hi/lo
  transpose_cvt_split<<<dim3(XDIM / 32, INDIM / 32), dim3(32, 8), 0, stream>>>(
      W_in, (unsigned short*)w_in_s, (unsigned short*)(w_in_s + wpl_in), INDIM,
      XDIM);
  for (int i = 0; i < 6; i++)
    transpose_cvt_split<<<dim3(XDIM / 32, hin[i] / 32), dim3(32, 8), 0,
                          stream>>>(Wh[i], (unsigned short*)w_h_s[i],
                                    (unsigned short*)(w_h_s[i] + wpl_h[i]),
                                    hin[i], XDIM);
  transpose_cvt_split<<<dim3(OUTDIM / 32, XDIM / 32), dim3(32, 8), 0,
                        stream>>>(W_out, (unsigned short*)w_out_s,
                                  (unsigned short*)(w_out_s + wpl_out), XDIM,
                                  OUTDIM);

  // 3) GEMM chain with 3 rotating activation buffers
  auto G = [&](const short* A1, size_t a1pl, const short* A2, size_t a2pl,
               const short* W, size_t wpl, const float* bi, const float* m,
               const int* a, short* Cb, float* Cf, int N, int K, int Ks) {
    dim3 grid(N / 128, BDIM / 64);
    const short* A2h = A2;
    const short* A2l = A2 ? A2 + a2pl : nullptr;
    if (Cb)
      gemm_split_act<true><<<grid, 256, 0, stream>>>(
          A1, A1 + a1pl, A2h, A2l, W, W + wpl, bi, m, a, (unsigned short*)Cb,
          (unsigned short*)(Cb + apl), nullptr, N, K, Ks);
    else
      gemm_split_act<false><<<grid, 256, 0, stream>>>(
          A1, A1 + a1pl, A2h, A2l, W, W + wpl, bi, m, a, nullptr, nullptr, Cf,
          N, K, Ks);
  };

  // input layer: outs[0]=actA
  G(x_s, xpl, nullptr, 0, w_in_s, wpl_in, b_in, mo_in, aid_in, actA, nullptr,
    XDIM, INDIM, INDIM);
  // L0: outs[1]=actB
  G(actA, apl, nullptr, 0, w_h_s[0], wpl_h[0], bh + 0 * XDIM, mo_h + 0 * XDIM,
    aid_h + 0 * XDIM, actB, nullptr, XDIM, XDIM, XDIM);
  // L1: outs[2]=actC
  G(actB, apl, nullptr, 0, w_h_s[1], wpl_h[1], bh + 1 * XDIM, mo_h + 1 * XDIM,
    aid_h + 1 * XDIM, actC, nullptr, XDIM, XDIM, XDIM);
  // L2 (concat outs2,outs1): outs[3]=actA
  G(actC, apl, actB, apl, w_h_s[2], wpl_h[2], bh + 2 * XDIM, mo_h + 2 * XDIM,
    aid_h + 2 * XDIM, actA, nullptr, XDIM, 2 * XDIM, XDIM);
  // L3: outs[4]=actB
  G(actA, apl, nullptr, 0, w_h_s[3], wpl_h[3], bh + 3 * XDIM, mo_h + 3 * XDIM,
    aid_h + 3 * XDIM, actB, nullptr, XDIM, XDIM, XDIM);
  // L4 (concat outs4,outs3): outs[5]=actC
  G(actB, apl, actA, apl, w_h_s[4], wpl_h[4], bh + 4 * XDIM, mo_h + 4 * XDIM,
    aid_h + 4 * XDIM, actC, nullptr, XDIM, 2 * XDIM, XDIM);
  // L5: outs[6]=actB
  G(actC, apl, nullptr, 0, w_h_s[5], wpl_h[5], bh + 5 * XDIM, mo_h + 5 * XDIM,
    aid_h + 5 * XDIM, actB, nullptr, XDIM, XDIM, XDIM);
  // output layer -> d_out (fp32)
  G(actB, apl, nullptr, 0, w_out_s, wpl_out, b_out, mo_out, aid_out, nullptr,
    (float*)d_out, OUTDIM, XDIM, XDIM);
}

// Round 8
// 2018.887 us; speedup vs baseline: 1.1922x; 1.1922x over previous
//
#include <hip/hip_runtime.h>
#include <stdint.h>
#include <string.h>

// Problem dims (fixed by the reference)
#define BDIM   4096
#define INDIM  1024
#define XDIM   2048
#define OUTDIM 512

#define LO_SCALE 2048.0f         // 2^11: lifts fp16 lo-plane out of subnormals
#define INV_LO_SCALE (1.0f / 2048.0f)

typedef _Float16 f16x8 __attribute__((ext_vector_type(8)));
typedef float f32x4 __attribute__((ext_vector_type(4)));

__device__ __forceinline__ unsigned short h2u(_Float16 h) {
  unsigned short u;
  memcpy(&u, &h, 2);
  return u;
}

// split f32 into hi fp16 + scaled-lo fp16 (combined ~22 mantissa bits)
__device__ __forceinline__ void split_h(float v, unsigned short& h,
                                        unsigned short& l) {
  _Float16 hh = (_Float16)v;                       // RTNE
  float r = v - (float)hh;                         // exact
  _Float16 ll = (_Float16)(r * LO_SCALE);          // |r|*2^11 <= |v|, no inf
  h = h2u(hh);
  l = h2u(ll);
}

// async global->LDS, 16B per lane; LDS dest wave-uniform base + lane*16
__device__ __forceinline__ void gld_lds16(const void* g, void* l) {
  __builtin_amdgcn_global_load_lds(
      (const __attribute__((address_space(1))) uint32_t*)g,
      (__attribute__((address_space(3))) uint32_t*)l, 16, 0, 0);
}

// fused RandomActivation + clip (relu/sigmoid/tanh/leaky(.1)/selu), libm-grade
__device__ __forceinline__ float rand_act(float v, int a, float mo) {
  float r;
  if (a == 0) {
    r = fmaxf(v, 0.0f);
  } else if (a == 1) {
    r = 1.0f / (1.0f + expf(-v));
  } else if (a == 2) {
    r = tanhf(v);
  } else if (a == 3) {
    r = (v >= 0.0f) ? v : 0.1f * v;
  } else {  // selu (matches jax: scale * where(v>0, v, alpha*expm1(v)))
    r = (v > 0.0f) ? 1.0507009873554805f * v
                   : 1.7580993408473766f * expm1f(v);
  }
  return fminf(r, mo);
}

// x (f32) -> hi/scaled-lo fp16 planes, 4 elems/thread
__global__ void cvt_split(const float* __restrict__ s,
                          unsigned short* __restrict__ dh,
                          unsigned short* __restrict__ dl, int n) {
  int i = (blockIdx.x * blockDim.x + threadIdx.x) * 4;
  if (i >= n) return;
  float4 v = *(const float4*)(s + i);
  ushort4 h, l;
  split_h(v.x, h.x, l.x);
  split_h(v.y, h.y, l.y);
  split_h(v.z, h.z, l.z);
  split_h(v.w, h.w, l.w);
  *(ushort4*)(dh + i) = h;
  *(ushort4*)(dl + i) = l;
}

// W (K x N, f32, row-major) -> WT hi/scaled-lo fp16 (N x K, row-major)
__global__ void transpose_cvt_split(const float* __restrict__ W,
                                    unsigned short* __restrict__ WTh,
                                    unsigned short* __restrict__ WTl, int K,
                                    int N) {
  __shared__ float t[32][33];
  int n0 = blockIdx.x * 32, k0 = blockIdx.y * 32;
  int tx = threadIdx.x, ty = threadIdx.y;  // 32 x 8
#pragma unroll
  for (int i = 0; i < 32; i += 8)
    t[ty + i][tx] = W[(size_t)(k0 + ty + i) * N + n0 + tx];
  __syncthreads();
#pragma unroll
  for (int i = 0; i < 32; i += 8) {
    float v = t[tx][ty + i];
    unsigned short h, l;
    split_h(v, h, l);
    size_t idx = (size_t)(n0 + ty + i) * K + k0 + tx;
    WTh[idx] = h;
    WTl[idx] = l;
  }
}

// C[M,N] = act( A[M,K] @ BT[N,K]^T + bias ), split-fp16 (3-term) precision.
// acc1 = hi*hi; acc2 = hi*lo' + lo'*hi at scale 2^11. Final = acc1+acc2/2^11.
//
// Round-8 = Round-4 (best measured: concat 283 us, total 1491 us) with the
// ONE verified orthogonal fix folded in: FRAGMENT-ORDER LDS staging (R5/R6/R7
// all measured SQ_LDS_BANK_CONFLICT == 0 with it; R4 paid 2.5e7 conflict
// cycles/dispatch with [m][k]-layout tiles). Everything else is R4:
//  - A and B both staged via global_load_lds DMA (barrier-locked lockstep --
//    R7 proved per-lane B loads + prefetch doubles HBM FETCH via L2 thrash),
//  - single buffer, 24 KB LDS, two barriers per K-step,
//  - block tile 64x128, BK=32, 4 waves (wave-tile 64x32), grid (N/128, M/64)
//    -> 1024 blocks = 4 blocks/CU co-resident (the R3->R4 2x win).
// LDS layout: lA = 8 chunks of 1 KB ([plane2][t4]); lB = 16 chunks
// ([plane2][r8]). Chunk c staged so lane i writes exactly the 16 B that
// compute-lane i reads: one contiguous 1-KB ds_read_b128 per fragment.
template <bool OUT_F16>
__global__ __launch_bounds__(256, 4) void gemm_split_act(
    const short* __restrict__ A1h, const short* __restrict__ A1l,
    const short* __restrict__ A2h, const short* __restrict__ A2l,
    const short* __restrict__ BTh, const short* __restrict__ BTl,
    const float* __restrict__ bias, const float* __restrict__ mo,
    const int* __restrict__ aid, unsigned short* __restrict__ Ch,
    unsigned short* __restrict__ Cl, float* __restrict__ Cf, int N, int K,
    int Ksplit) {
  __shared__ short lA[8 * 512];   // 8 KB
  __shared__ short lB[16 * 512];  // 16 KB

  const int tid = threadIdx.x;
  const int lane = tid & 63;
  const int wave = tid >> 6;        // 0..3 = n-strip of wave
  const int m16 = lane & 15, quad = lane >> 4;

  const int blockN = blockIdx.x * 128;
  const int blockM = blockIdx.y * 64;

  f32x4 acc1[4][2];  // hi*hi
  f32x4 acc2[4][2];  // (hi*lo' + lo'*hi), scale 2^11
#pragma unroll
  for (int i = 0; i < 4; i++)
#pragma unroll
    for (int j = 0; j < 2; j++) {
      acc1[i][j] = (f32x4){0.f, 0.f, 0.f, 0.f};
      acc2[i][j] = (f32x4){0.f, 0.f, 0.f, 0.f};
    }

  for (int k0 = 0; k0 < K; k0 += 32) {
    const short *Akh, *Akl;
    int koff, lda;
    if (k0 < Ksplit) {
      Akh = A1h; Akl = A1l; koff = k0; lda = Ksplit;
    } else {
      Akh = A2h; Akl = A2l; koff = k0 - Ksplit; lda = K - Ksplit;
    }

    __syncthreads();  // previous iter's ds_reads done before overwrite

    // stage 24 chunks of 1 KB, 6 per wave, fragment order.
#pragma unroll
    for (int s = 0; s < 6; s++) {
      int g = wave * 6 + s;
      if (g < 8) {                       // A chunk: plane=g>>2, t=g&3
        int t = g & 3;
        const short* base = (g < 4) ? Akh : Akl;
        const short* src =
            base + (size_t)(blockM + t * 16 + m16) * lda + koff + quad * 8;
        gld_lds16(src, lA + g * 512);
      } else {                           // B chunk: c=g-8, plane=c>>3, r=c&7
        int c = g - 8;
        int r = c & 7;
        const short* base = (c < 8) ? BTh : BTl;
        const short* src =
            base + (size_t)(blockN + r * 16 + m16) * K + k0 + quad * 8;
        gld_lds16(src, lB + c * 512);
      }
    }
    __syncthreads();  // drains vmcnt: tiles visible

    // compute: every fragment read is one contiguous 1-KB ds_read_b128.
    f16x8 aH[4], bH[2];
#pragma unroll
    for (int t = 0; t < 4; t++)
      aH[t] = *(const f16x8*)&lA[t * 512 + lane * 8];
#pragma unroll
    for (int j = 0; j < 2; j++)
      bH[j] = *(const f16x8*)&lB[(wave * 2 + j) * 512 + lane * 8];
    // phase 1: hi x hi -> acc1
#pragma unroll
    for (int i = 0; i < 4; i++)
#pragma unroll
      for (int j = 0; j < 2; j++)
        acc1[i][j] = __builtin_amdgcn_mfma_f32_16x16x32_f16(aH[i], bH[j],
                                                            acc1[i][j], 0, 0, 0);
    // phase 2: hi x lo' -> acc2
    {
      f16x8 bL[2];
#pragma unroll
      for (int j = 0; j < 2; j++)
        bL[j] = *(const f16x8*)&lB[(8 + wave * 2 + j) * 512 + lane * 8];
#pragma unroll
      for (int i = 0; i < 4; i++)
#pragma unroll
        for (int j = 0; j < 2; j++)
          acc2[i][j] = __builtin_amdgcn_mfma_f32_16x16x32_f16(
              aH[i], bL[j], acc2[i][j], 0, 0, 0);
    }
    // phase 3: lo' x hi -> acc2
    {
      f16x8 aL[4];
#pragma unroll
      for (int t = 0; t < 4; t++)
        aL[t] = *(const f16x8*)&lA[(4 + t) * 512 + lane * 8];
#pragma unroll
      for (int i = 0; i < 4; i++)
#pragma unroll
        for (int j = 0; j < 2; j++)
          acc2[i][j] = __builtin_amdgcn_mfma_f32_16x16x32_f16(
              aL[i], bH[j], acc2[i][j], 0, 0, 0);
    }
  }

  // epilogue: combine accs, bias + per-column activation + clip
  // C/D map col=lane&15, row=quad*4+reg (m89-verified)
#pragma unroll
  for (int j = 0; j < 2; j++) {
    int col = blockN + wave * 32 + j * 16 + m16;
    float b = bias[col];
    float m = mo[col];
    int a = aid[col];
#pragma unroll
    for (int i = 0; i < 4; i++) {
#pragma unroll
      for (int r = 0; r < 4; r++) {
        int row = blockM + i * 16 + quad * 4 + r;
        float s = acc1[i][j][r] + acc2[i][j][r] * INV_LO_SCALE;
        float v = rand_act(s + b, a, m);
        size_t idx = (size_t)row * N + col;
        if (OUT_F16) {
          unsigned short h, l;
          split_h(v, h, l);
          Ch[idx] = h;
          Cl[idx] = l;
        } else {
          Cf[idx] = v;
        }
      }
    }
  }
}

extern "C" void kernel_launch(void* const* d_in, const int* in_sizes, int n_in,
                              void* d_out, int out_size, void* d_ws,
                              size_t ws_size, hipStream_t stream) {
  (void)in_sizes; (void)n_in; (void)out_size; (void)ws_size;

  const float* x     = (const float*)d_in[0];
  const float* W_in  = (const float*)d_in[1];
  const float* b_in  = (const float*)d_in[2];
  const float* Wh[6] = {(const float*)d_in[3], (const float*)d_in[4],
                        (const float*)d_in[5], (const float*)d_in[6],
                        (const float*)d_in[7], (const float*)d_in[8]};
  const float* bh    = (const float*)d_in[9];
  const float* W_out = (const float*)d_in[10];
  const float* b_out = (const float*)d_in[11];
  const float* mo_in = (const float*)d_in[12];
  const float* mo_h  = (const float*)d_in[13];
  const float* mo_out= (const float*)d_in[14];
  const int* aid_in  = (const int*)d_in[15];
  const int* aid_h   = (const int*)d_in[16];
  const int* aid_out = (const int*)d_in[17];

  const int hin[6] = {XDIM, XDIM, 2 * XDIM, XDIM, 2 * XDIM, XDIM};

  // workspace layout (~264 MB); each tensor = hi plane then lo plane
  char* p = (char*)d_ws;
  auto take = [&](size_t elems) {
    short* q = (short*)p;
    p += elems * 2 * 2;  // hi + lo, 2B each
    return q;
  };
  short* x_s = take((size_t)BDIM * INDIM);
  size_t xpl = (size_t)BDIM * INDIM;
  short* w_in_s = take((size_t)XDIM * INDIM);
  size_t wpl_in = (size_t)XDIM * INDIM;
  short* w_h_s[6];
  size_t wpl_h[6];
  for (int i = 0; i < 6; i++) {
    wpl_h[i] = (size_t)XDIM * hin[i];
    w_h_s[i] = take(wpl_h[i]);
  }
  short* w_out_s = take((size_t)OUTDIM * XDIM);
  size_t wpl_out = (size_t)OUTDIM * XDIM;
  const size_t apl = (size_t)BDIM * XDIM;  // activation plane
  short* actA = take(apl);
  short* actB = take(apl);
  short* actC = take(apl);

  // 1) convert x -> hi/lo fp16
  {
    int n = BDIM * INDIM;
    cvt_split<<<dim3(n / 4 / 256), dim3(256), 0, stream>>>(
        x, (unsigned short*)x_s, (unsigned short*)(x_s + xpl), n);
  }
  // 2) transpose+split all weights: W(K,N) -> WT(N,K) hi/lo
  transpose_cvt_split<<<dim3(XDIM / 32, INDIM / 32), dim3(32, 8), 0, stream>>>(
      W_in, (unsigned short*)w_in_s, (unsigned short*)(w_in_s + wpl_in), INDIM,
      XDIM);
  for (int i = 0; i < 6; i++)
    transpose_cvt_split<<<dim3(XDIM / 32, hin[i] / 32), dim3(32, 8), 0,
                          stream>>>(Wh[i], (unsigned short*)w_h_s[i],
                                    (unsigned short*)(w_h_s[i] + wpl_h[i]),
                                    hin[i], XDIM);
  transpose_cvt_split<<<dim3(OUTDIM / 32, XDIM / 32), dim3(32, 8), 0,
                        stream>>>(W_out, (unsigned short*)w_out_s,
                                  (unsigned short*)(w_out_s + wpl_out), XDIM,
                                  OUTDIM);

  // 3) GEMM chain with 3 rotating activation buffers
  auto G = [&](const short* A1, size_t a1pl, const short* A2, size_t a2pl,
               const short* W, size_t wpl, const float* bi, const float* m,
               const int* a, short* Cb, float* Cf, int N, int K, int Ks) {
    dim3 grid(N / 128, BDIM / 64);
    const short* A2h = A2;
    const short* A2l = A2 ? A2 + a2pl : nullptr;
    if (Cb)
      gemm_split_act<true><<<grid, 256, 0, stream>>>(
          A1, A1 + a1pl, A2h, A2l, W, W + wpl, bi, m, a, (unsigned short*)Cb,
          (unsigned short*)(Cb + apl), nullptr, N, K, Ks);
    else
      gemm_split_act<false><<<grid, 256, 0, stream>>>(
          A1, A1 + a1pl, A2h, A2l, W, W + wpl, bi, m, a, nullptr, nullptr, Cf,
          N, K, Ks);
  };

  // input layer: outs[0]=actA
  G(x_s, xpl, nullptr, 0, w_in_s, wpl_in, b_in, mo_in, aid_in, actA, nullptr,
    XDIM, INDIM, INDIM);
  // L0: outs[1]=actB
  G(actA, apl, nullptr, 0, w_h_s[0], wpl_h[0], bh + 0 * XDIM, mo_h + 0 * XDIM,
    aid_h + 0 * XDIM, actB, nullptr, XDIM, XDIM, XDIM);
  // L1: outs[2]=actC
  G(actB, apl, nullptr, 0, w_h_s[1], wpl_h[1], bh + 1 * XDIM, mo_h + 1 * XDIM,
    aid_h + 1 * XDIM, actC, nullptr, XDIM, XDIM, XDIM);
  // L2 (concat outs2,outs1): outs[3]=actA
  G(actC, apl, actB, apl, w_h_s[2], wpl_h[2], bh + 2 * XDIM, mo_h + 2 * XDIM,
    aid_h + 2 * XDIM, actA, nullptr, XDIM, 2 * XDIM, XDIM);
  // L3: outs[4]=actB
  G(actA, apl, nullptr, 0, w_h_s[3], wpl_h[3], bh + 3 * XDIM, mo_h + 3 * XDIM,
    aid_h + 3 * XDIM, actB, nullptr, XDIM, XDIM, XDIM);
  // L4 (concat outs4,outs3): outs[5]=actC
  G(actB, apl, actA, apl, w_h_s[4], wpl_h[4], bh + 4 * XDIM, mo_h + 4 * XDIM,
    aid_h + 4 * XDIM, actC, nullptr, XDIM, 2 * XDIM, XDIM);
  // L5: outs[6]=actB
  G(actC, apl, nullptr, 0, w_h_s[5], wpl_h[5], bh + 5 * XDIM, mo_h + 5 * XDIM,
    aid_h + 5 * XDIM, actB, nullptr, XDIM, XDIM, XDIM);
  // output layer -> d_out (fp32)
  G(actB, apl, nullptr, 0, w_out_s, wpl_out, b_out, mo_out, aid_out, nullptr,
    (float*)d_out, OUTDIM, XDIM, XDIM);
}

// Round 9
// 1145.262 us; speedup vs baseline: 2.1017x; 1.7628x over previous
//
#include <hip/hip_runtime.h>
#include <stdint.h>
#include <string.h>

// Problem dims (fixed by the reference)
#define BDIM   4096
#define INDIM  1024
#define XDIM   2048
#define OUTDIM 512
#define MCH    (BDIM / 16)   // 256 row-chunks along M for packed activations

#define LO_SCALE 2048.0f         // 2^11: lifts fp16 lo-plane out of subnormals
#define INV_LO_SCALE (1.0f / 2048.0f)

typedef _Float16 f16x8 __attribute__((ext_vector_type(8)));
typedef float f32x4 __attribute__((ext_vector_type(4)));

__device__ __forceinline__ unsigned short h2u(_Float16 h) {
  unsigned short u;
  memcpy(&u, &h, 2);
  return u;
}

// split f32 into hi fp16 + scaled-lo fp16 (combined ~22 mantissa bits)
__device__ __forceinline__ void split_h(float v, unsigned short& h,
                                        unsigned short& l) {
  _Float16 hh = (_Float16)v;                       // RTNE
  float r = v - (float)hh;                         // exact
  _Float16 ll = (_Float16)(r * LO_SCALE);          // |r|*2^11 <= |v|, no inf
  h = h2u(hh);
  l = h2u(ll);
}

// async global->LDS, 16B per lane; LDS dest wave-uniform base + lane*16
__device__ __forceinline__ void gld_lds16(const void* g, void* l) {
  __builtin_amdgcn_global_load_lds(
      (const __attribute__((address_space(1))) uint32_t*)g,
      (__attribute__((address_space(3))) uint32_t*)l, 16, 0, 0);
}

// fused RandomActivation + clip (relu/sigmoid/tanh/leaky(.1)/selu), libm-grade
__device__ __forceinline__ float rand_act(float v, int a, float mo) {
  float r;
  if (a == 0) {
    r = fmaxf(v, 0.0f);
  } else if (a == 1) {
    r = 1.0f / (1.0f + expf(-v));
  } else if (a == 2) {
    r = tanhf(v);
  } else if (a == 3) {
    r = (v >= 0.0f) ? v : 0.1f * v;
  } else {  // selu (matches jax: scale * where(v>0, v, alpha*expm1(v)))
    r = (v > 0.0f) ? 1.0507009873554805f * v
                   : 1.7580993408473766f * expm1f(v);
  }
  return fminf(r, mo);
}

// ---------------------------------------------------------------------------
// PACKED LAYOUT (the R4-vs-R8 resolution): tensor X[rows][K] is stored as
//   packed[k/32][row/16][lane(64)][8 halfs],
// lane = quad*16 + m16 holding X[chunkrow*16 + m16][kstep*32 + quad*8 + j].
// Each (kstep,chunk) = contiguous 1 KB: staging DMA is consecutive-lane-
// contiguous (R4's coalescing) AND compute ds_read_b128 is contiguous
// (R8's zero conflicts). Concat along K = packed tensors back-to-back.
// ---------------------------------------------------------------------------

// x[BDIM][Kin] f32 row-major -> packed hi/lo planes. grid(Kin/32, BDIM/64)x256
__global__ void pack_x(const float* __restrict__ s,
                       unsigned short* __restrict__ dh,
                       unsigned short* __restrict__ dl, int Kin) {
  int ks = blockIdx.x;
  int mblk = blockIdx.y;
  int cc = threadIdx.x >> 6;        // chunk within 64-row group
  int lane = threadIdx.x & 63;
  int m16 = lane & 15, quad = lane >> 4;
  int row = mblk * 64 + cc * 16 + m16;
  const float* src = s + (size_t)row * Kin + ks * 32 + quad * 8;
  size_t o = ((size_t)ks * MCH + mblk * 4 + cc) * 512 + lane * 8;
#pragma unroll
  for (int j = 0; j < 8; j++) {
    unsigned short h, l;
    split_h(src[j], h, l);
    dh[o + j] = h;
    dl[o + j] = l;
  }
}

// W[K][N] f32 row-major -> packed-BT hi/lo (rows=N, Kdim=K).
// grid(N/32, K/32), block(32,8).
__global__ void pack_w(const float* __restrict__ W,
                       unsigned short* __restrict__ dh,
                       unsigned short* __restrict__ dl, int K, int N) {
  __shared__ float t[32][33];       // t[k'][n']
  int n0 = blockIdx.x * 32, k0 = blockIdx.y * 32;
  int tx = threadIdx.x, ty = threadIdx.y;
#pragma unroll
  for (int i = 0; i < 32; i += 8)
    t[ty + i][tx] = W[(size_t)(k0 + ty + i) * N + n0 + tx];
  __syncthreads();
  int tt = ty * 32 + tx;            // 0..255
  int ci = tt >> 7;                 // n-chunk 0/1
  int rem = tt & 127;
  int lane = rem >> 1;
  int j4 = (rem & 1) * 4;
  int m16 = lane & 15, quad = lane >> 4;
  size_t o = ((size_t)(k0 >> 5) * (N >> 4) + (n0 >> 4) + ci) * 512 +
             lane * 8 + j4;
#pragma unroll
  for (int jj = 0; jj < 4; jj++) {
    float v = t[quad * 8 + j4 + jj][ci * 16 + m16];
    unsigned short h, l;
    split_h(v, h, l);
    dh[o + jj] = h;
    dl[o + jj] = l;
  }
}

// C[M,N] = act( A[M,K] @ BT[N,K]^T + bias ), split-fp16 (3-term) precision.
// acc1 = hi*hi; acc2 = hi*lo' + lo'*hi at scale 2^11. Final = acc1+acc2/2^11.
//
// Round-9 structure (packed layouts resolve R4/R8 tradeoff; R6/R7 fixes
// folded back in with their failure causes removed):
//  - A: LDS double-buffer 2 x 8 KB (16 KB total -> 4 blocks/CU, unlike R6's
//    48 KB), staged by global_load_lds from packed chunks: coalesced AND
//    fragment-ordered (conflict-free reads).
//  - B: global -> VGPR from packed 1-KB chunks (coalesced; R7's per-lane
//    strided loads are gone), prefetched one K-step ahead.
//  - one __syncthreads per K-step; prefetch issued a full compute phase
//    before its drain.
// Block tile 64x128, BK=32, 4 waves (wave-tile 64x32). Grid (N/128, M/64).
template <bool OUT_F16>
__global__ __launch_bounds__(256, 4) void gemm_split_act(
    const short* __restrict__ A1h, const short* __restrict__ A1l,
    const short* __restrict__ A2h, const short* __restrict__ A2l,
    const short* __restrict__ BTh, const short* __restrict__ BTl,
    const float* __restrict__ bias, const float* __restrict__ mo,
    const int* __restrict__ aid, unsigned short* __restrict__ Ch,
    unsigned short* __restrict__ Cl, float* __restrict__ Cf, int N, int K,
    int Ksplit) {
  __shared__ short lA0[8 * 512];   // 8 KB: chunks 0-3 hi, 4-7 lo
  __shared__ short lA1[8 * 512];

  const int tid = threadIdx.x;
  const int lane = tid & 63;
  const int wave = tid >> 6;        // 0..3 = n-strip of wave
  const int m16 = lane & 15, quad = lane >> 4;

  const int blockN = blockIdx.x * 128;
  const int blockM = blockIdx.y * 64;

  f32x4 acc1[4][2];  // hi*hi
  f32x4 acc2[4][2];  // (hi*lo' + lo'*hi), scale 2^11
#pragma unroll
  for (int i = 0; i < 4; i++)
#pragma unroll
    for (int j = 0; j < 2; j++) {
      acc1[i][j] = (f32x4){0.f, 0.f, 0.f, 0.f};
      acc2[i][j] = (f32x4){0.f, 0.f, 0.f, 0.f};
    }

  const int KSTEPS = K >> 5;        // 32/64/128 — always even
  const int KS1 = Ksplit >> 5;

  // stage A kstep ks into dA (8 chunks of 1 KB, 2 per wave, packed source)
  auto stageA = [&](int ks, short* dA) {
    const short *ph, *pl;
    int kk;
    if (ks < KS1) { ph = A1h; pl = A1l; kk = ks; }
    else          { ph = A2h; pl = A2l; kk = ks - KS1; }
    size_t base = ((size_t)kk * MCH + (blockM >> 4)) * 512 + lane * 8;
#pragma unroll
    for (int s = 0; s < 2; s++) {
      int g = wave * 2 + s;          // 0..7
      int t = g & 3;
      const short* plane = (g < 4) ? ph : pl;
      gld_lds16(plane + base + t * 512, dA + g * 512);
    }
  };

  // load B fragments for kstep ks from packed chunks (coalesced 1 KB each)
  auto loadB = [&](int ks, f16x8* bH, f16x8* bL) {
    size_t base =
        ((size_t)ks * (N >> 4) + (blockN >> 4) + wave * 2) * 512 + lane * 8;
    bH[0] = *(const f16x8*)(BTh + base);
    bH[1] = *(const f16x8*)(BTh + base + 512);
    bL[0] = *(const f16x8*)(BTl + base);
    bL[1] = *(const f16x8*)(BTl + base + 512);
  };

  auto compute = [&](const short* sA, const f16x8* bH, const f16x8* bL) {
    f16x8 aH[4];
#pragma unroll
    for (int t = 0; t < 4; t++)
      aH[t] = *(const f16x8*)&sA[t * 512 + lane * 8];
    // phase 1: hi x hi -> acc1
#pragma unroll
    for (int i = 0; i < 4; i++)
#pragma unroll
      for (int j = 0; j < 2; j++)
        acc1[i][j] = __builtin_amdgcn_mfma_f32_16x16x32_f16(aH[i], bH[j],
                                                            acc1[i][j], 0, 0, 0);
    // phase 2: hi x lo' -> acc2
#pragma unroll
    for (int i = 0; i < 4; i++)
#pragma unroll
      for (int j = 0; j < 2; j++)
        acc2[i][j] = __builtin_amdgcn_mfma_f32_16x16x32_f16(aH[i], bL[j],
                                                            acc2[i][j], 0, 0, 0);
    // phase 3: lo' x hi -> acc2
    f16x8 aL[4];
#pragma unroll
    for (int t = 0; t < 4; t++)
      aL[t] = *(const f16x8*)&sA[(4 + t) * 512 + lane * 8];
#pragma unroll
    for (int i = 0; i < 4; i++)
#pragma unroll
      for (int j = 0; j < 2; j++)
        acc2[i][j] = __builtin_amdgcn_mfma_f32_16x16x32_f16(aL[i], bH[j],
                                                            acc2[i][j], 0, 0, 0);
  };

  f16x8 bH0[2], bL0[2], bH1[2], bL1[2];

  stageA(0, lA0);
  loadB(0, bH0, bL0);
  __syncthreads();  // prologue drain (full latency once)

  for (int ks = 0; ks < KSTEPS; ks += 2) {
    // prefetch ks+1 (A-DMA + B-regs), then compute ks: the barrier drain is
    // overlapped by a full compute phase.
    stageA(ks + 1, lA1);             // ks+1 < KSTEPS always (KSTEPS even)
    loadB(ks + 1, bH1, bL1);
    compute(lA0, bH0, bL0);
    __syncthreads();
    if (ks + 2 < KSTEPS) {
      stageA(ks + 2, lA0);
      loadB(ks + 2, bH0, bL0);
    }
    compute(lA1, bH1, bL1);
    __syncthreads();
  }

  // epilogue: combine accs, bias + per-column activation + clip.
  // C/D map col=lane&15, row=quad*4+reg (m89-verified).
  // OUT_F16 path writes PACKED layout (next layer's A): chunkrow=row>>4,
  // kstep=col>>5, lane'=((col>>3)&3)*16 + (row&15), j'=col&7.
#pragma unroll
  for (int j = 0; j < 2; j++) {
    int col = blockN + wave * 32 + j * 16 + m16;
    float b = bias[col];
    float m = mo[col];
    int a = aid[col];
    size_t kbase = OUT_F16 ? ((size_t)(col >> 5) * MCH) * 512 +
                                 (size_t)((col >> 3) & 3) * 128 + (col & 7)
                           : 0;
#pragma unroll
    for (int i = 0; i < 4; i++) {
#pragma unroll
      for (int r = 0; r < 4; r++) {
        int row = blockM + i * 16 + quad * 4 + r;
        float s = acc1[i][j][r] + acc2[i][j][r] * INV_LO_SCALE;
        float v = rand_act(s + b, a, m);
        if (OUT_F16) {
          unsigned short h, l;
          split_h(v, h, l);
          size_t pidx = kbase + (size_t)(row >> 4) * 512 + (row & 15) * 8;
          Ch[pidx] = h;
          Cl[pidx] = l;
        } else {
          Cf[(size_t)row * N + col] = v;
        }
      }
    }
  }
}

extern "C" void kernel_launch(void* const* d_in, const int* in_sizes, int n_in,
                              void* d_out, int out_size, void* d_ws,
                              size_t ws_size, hipStream_t stream) {
  (void)in_sizes; (void)n_in; (void)out_size; (void)ws_size;

  const float* x     = (const float*)d_in[0];
  const float* W_in  = (const float*)d_in[1];
  const float* b_in  = (const float*)d_in[2];
  const float* Wh[6] = {(const float*)d_in[3], (const float*)d_in[4],
                        (const float*)d_in[5], (const float*)d_in[6],
                        (const float*)d_in[7], (const float*)d_in[8]};
  const float* bh    = (const float*)d_in[9];
  const float* W_out = (const float*)d_in[10];
  const float* b_out = (const float*)d_in[11];
  const float* mo_in = (const float*)d_in[12];
  const float* mo_h  = (const float*)d_in[13];
  const float* mo_out= (const float*)d_in[14];
  const int* aid_in  = (const int*)d_in[15];
  const int* aid_h   = (const int*)d_in[16];
  const int* aid_out = (const int*)d_in[17];

  const int hin[6] = {XDIM, XDIM, 2 * XDIM, XDIM, 2 * XDIM, XDIM};

  // workspace layout (~264 MB); each tensor = hi plane then lo plane (packed)
  char* p = (char*)d_ws;
  auto take = [&](size_t elems) {
    short* q = (short*)p;
    p += elems * 2 * 2;  // hi + lo, 2B each
    return q;
  };
  short* x_s = take((size_t)BDIM * INDIM);
  size_t xpl = (size_t)BDIM * INDIM;
  short* w_in_s = take((size_t)XDIM * INDIM);
  size_t wpl_in = (size_t)XDIM * INDIM;
  short* w_h_s[6];
  size_t wpl_h[6];
  for (int i = 0; i < 6; i++) {
    wpl_h[i] = (size_t)XDIM * hin[i];
    w_h_s[i] = take(wpl_h[i]);
  }
  short* w_out_s = take((size_t)OUTDIM * XDIM);
  size_t wpl_out = (size_t)OUTDIM * XDIM;
  const size_t apl = (size_t)BDIM * XDIM;  // activation plane
  short* actA = take(apl);
  short* actB = take(apl);
  short* actC = take(apl);

  // 1) pack x -> hi/lo fp16 packed
  pack_x<<<dim3(INDIM / 32, BDIM / 64), dim3(256), 0, stream>>>(
      x, (unsigned short*)x_s, (unsigned short*)(x_s + xpl), INDIM);
  // 2) pack all weights: W(K,N) -> packed BT(rows=N, Kdim=K) hi/lo
  pack_w<<<dim3(XDIM / 32, INDIM / 32), dim3(32, 8), 0, stream>>>(
      W_in, (unsigned short*)w_in_s, (unsigned short*)(w_in_s + wpl_in), INDIM,
      XDIM);
  for (int i = 0; i < 6; i++)
    pack_w<<<dim3(XDIM / 32, hin[i] / 32), dim3(32, 8), 0, stream>>>(
        Wh[i], (unsigned short*)w_h_s[i],
        (unsigned short*)(w_h_s[i] + wpl_h[i]), hin[i], XDIM);
  pack_w<<<dim3(OUTDIM / 32, XDIM / 32), dim3(32, 8), 0, stream>>>(
      W_out, (unsigned short*)w_out_s, (unsigned short*)(w_out_s + wpl_out),
      XDIM, OUTDIM);

  // 3) GEMM chain with 3 rotating activation buffers
  auto G = [&](const short* A1, size_t a1pl, const short* A2, size_t a2pl,
               const short* W, size_t wpl, const float* bi, const float* m,
               const int* a, short* Cb, float* Cf, int N, int K, int Ks) {
    dim3 grid(N / 128, BDIM / 64);
    const short* A2h = A2;
    const short* A2l = A2 ? A2 + a2pl : nullptr;
    if (Cb)
      gemm_split_act<true><<<grid, 256, 0, stream>>>(
          A1, A1 + a1pl, A2h, A2l, W, W + wpl, bi, m, a, (unsigned short*)Cb,
          (unsigned short*)(Cb + apl), nullptr, N, K, Ks);
    else
      gemm_split_act<false><<<grid, 256, 0, stream>>>(
          A1, A1 + a1pl, A2h, A2l, W, W + wpl, bi, m, a, nullptr, nullptr, Cf,
          N, K, Ks);
  };

  // input layer: outs[0]=actA
  G(x_s, xpl, nullptr, 0, w_in_s, wpl_in, b_in, mo_in, aid_in, actA, nullptr,
    XDIM, INDIM, INDIM);
  // L0: outs[1]=actB
  G(actA, apl, nullptr, 0, w_h_s[0], wpl_h[0], bh + 0 * XDIM, mo_h + 0 * XDIM,
    aid_h + 0 * XDIM, actB, nullptr, XDIM, XDIM, XDIM);
  // L1: outs[2]=actC
  G(actB, apl, nullptr, 0, w_h_s[1], wpl_h[1], bh + 1 * XDIM, mo_h + 1 * XDIM,
    aid_h + 1 * XDIM, actC, nullptr, XDIM, XDIM, XDIM);
  // L2 (concat outs2,outs1): outs[3]=actA
  G(actC, apl, actB, apl, w_h_s[2], wpl_h[2], bh + 2 * XDIM, mo_h + 2 * XDIM,
    aid_h + 2 * XDIM, actA, nullptr, XDIM, 2 * XDIM, XDIM);
  // L3: outs[4]=actB
  G(actA, apl, nullptr, 0, w_h_s[3], wpl_h[3], bh + 3 * XDIM, mo_h + 3 * XDIM,
    aid_h + 3 * XDIM, actB, nullptr, XDIM, XDIM, XDIM);
  // L4 (concat outs4,outs3): outs[5]=actC
  G(actB, apl, actA, apl, w_h_s[4], wpl_h[4], bh + 4 * XDIM, mo_h + 4 * XDIM,
    aid_h + 4 * XDIM, actC, nullptr, XDIM, 2 * XDIM, XDIM);
  // L5: outs[6]=actB
  G(actC, apl, nullptr, 0, w_h_s[5], wpl_h[5], bh + 5 * XDIM, mo_h + 5 * XDIM,
    aid_h + 5 * XDIM, actB, nullptr, XDIM, XDIM, XDIM);
  // output layer -> d_out (fp32, row-major)
  G(actB, apl, nullptr, 0, w_out_s, wpl_out, b_out, mo_out, aid_out, nullptr,
    (float*)d_out, OUTDIM, XDIM, XDIM);
}